// Round 5
// baseline (78.003 us; speedup 1.0000x reference)
//
#include <hip/hip_runtime.h>

// CategorySpecificLinear: out[t] = x[t] @ W[cid[t]] + bias[cid[t]]
// Pipeline: memset counts -> k_prep {W transpose->bf16 + bucketize}
//           -> grouped MFMA GEMM (A: in-kernel fp32->bf16 reg-staged;
//              B: global_load_lds depth-3; cat->XCD L2 partition).

typedef __attribute__((ext_vector_type(8))) short bf16x8;
typedef __attribute__((ext_vector_type(4))) float f32x4;
typedef __attribute__((ext_vector_type(8))) unsigned short ushort8_t;

__device__ __forceinline__ unsigned short f2bf(float f) {
  unsigned u = __float_as_uint(f);
  u += 0x7FFFu + ((u >> 16) & 1u);   // round-to-nearest-even
  return (unsigned short)(u >> 16);
}

// async global->LDS, 16B per lane; LDS dest = wave-uniform base + lane*16
__device__ __forceinline__ void gload_lds16(const unsigned short* g, unsigned short* l) {
  __builtin_amdgcn_global_load_lds(
      (const __attribute__((address_space(1))) unsigned int*)g,
      (__attribute__((address_space(3))) unsigned int*)l, 16, 0, 0);
}

// ---- kernel 1: W[c][d][o] fp32 -> Wt[c][o][d] bf16 (+ fused bucketize) ----
__global__ void k_prep(const float* __restrict__ W, unsigned short* __restrict__ Wt,
                       int Dd, int Oo,
                       const int* __restrict__ cid, int* __restrict__ counts,
                       int* __restrict__ bucket, int T) {
  int tid = threadIdx.x;
  int lid = blockIdx.x + gridDim.x * (blockIdx.y + gridDim.y * blockIdx.z);
  int tok = lid * 256 + tid;
  if (lid < (T + 255) / 256 && tok < T) {  // bucketize rides the first 16 blocks
    int cc = cid[tok];
    int p = atomicAdd(&counts[cc], 1);
    bucket[cc * T + p] = tok;
  }

  __shared__ float t[64][65];
  int c = blockIdx.z, d0 = blockIdx.y * 64, o0 = blockIdx.x * 64;
  const float* Wc = W + (size_t)c * Dd * Oo;
#pragma unroll
  for (int p = 0; p < 4; ++p) {
    int chunk = p * 256 + tid;
    int r  = chunk >> 4;
    int cb = chunk & 15;
    float4 v = *reinterpret_cast<const float4*>(Wc + (size_t)(d0 + r) * Oo + o0 + cb * 4);
    t[r][cb * 4 + 0] = v.x; t[r][cb * 4 + 1] = v.y;
    t[r][cb * 4 + 2] = v.z; t[r][cb * 4 + 3] = v.w;
  }
  __syncthreads();
  unsigned short* Wtc = Wt + (size_t)c * Oo * Dd;
#pragma unroll
  for (int p = 0; p < 2; ++p) {
    int chunk = p * 256 + tid;
    int orow = chunk >> 3;
    int dseg = chunk & 7;
    ushort8_t w;
#pragma unroll
    for (int j = 0; j < 8; ++j) w[j] = f2bf(t[dseg * 8 + j][orow]);
    *reinterpret_cast<ushort8_t*>(Wtc + (size_t)(o0 + orow) * Dd + d0 + dseg * 8) = w;
  }
}

// ---- kernel 2: grouped GEMM ----
// Grid (C, N, M): wgid % 8 == c -> per-XCD working set = Wt_c (2MB) + x_c (2MB fp32) -> L2.
#define BM 64
#define BN 128
#define BK 64
#define TA (BM * BK)   // 4096 bf16 = 8KB
#define TB (BN * BK)   // 8192 bf16 = 16KB

__global__ __launch_bounds__(256) void k_ggemm(
    const float* __restrict__ x, const unsigned short* __restrict__ Wt,
    const float* __restrict__ bias, const int* __restrict__ counts,
    const int* __restrict__ bucket, float* __restrict__ out,
    int T, int Dd, int Oo) {
  int c  = blockIdx.x;
  int Mc = counts[c];
  int m0 = blockIdx.z * BM;
  if (m0 >= Mc) return;  // block-uniform exit
  int n0 = blockIdx.y * BN;

  __shared__ __align__(16) unsigned short Al[2][TA];  // 16KB (A depth-2)
  __shared__ __align__(16) unsigned short Bl[3][TB];  // 48KB (B depth-3)

  const int tid  = threadIdx.x;
  const int lane = tid & 63;
  const int wid  = tid >> 6;
  const int wm   = wid >> 1, wn = wid & 1;  // 2x2 waves, each 32x64 of C

  const int* buck = bucket + c * T;
  const unsigned short* Wc = Wt + (size_t)c * Oo * Dd;

  // ---- B staging: 4 gload_lds per wave per tile (identical to R4) ----
  const unsigned short* bSrc[4];
  int bOff[4];
#pragma unroll
  for (int i = 0; i < 4; ++i) {
    int row = wid * 32 + i * 8 + (lane >> 3);
    int seg = (lane & 7) ^ (row & 7);        // pre-swizzled global source [rule 21]
    bSrc[i] = Wc + (size_t)(n0 + row) * Dd + seg * 8;
    bOff[i] = (wid * 32 + i * 8) * BK;
  }

  // ---- A staging: reg-staged fp32 gather + cvt + swizzled ds_write ----
  // thread -> row r = tid>>2, two 8-float segs s0 = tid&3, s1 = s0+4
  int ar   = tid >> 2;
  int s0   = tid & 3;
  int mrA  = m0 + ar;
  int tokA = buck[mrA < Mc ? mrA : Mc - 1];  // clamp; masked at epilogue
  const float* aG = x + (size_t)tokA * Dd + s0 * 8;
  int aW0 = ar * BK + ((s0    ) ^ (ar & 7)) * 8;
  int aW1 = ar * BK + ((s0 + 4) ^ (ar & 7)) * 8;

  float4 ra0, ra1, ra2, ra3;
#define LOADA(kt)  do { const float* p_ = aG + (kt) * BK;                    \
    ra0 = *reinterpret_cast<const float4*>(p_);                              \
    ra1 = *reinterpret_cast<const float4*>(p_ + 4);                          \
    ra2 = *reinterpret_cast<const float4*>(p_ + 32);                         \
    ra3 = *reinterpret_cast<const float4*>(p_ + 36); } while (0)
#define WRITEA(ab) do { ushort8_t w_;                                        \
    w_[0]=f2bf(ra0.x); w_[1]=f2bf(ra0.y); w_[2]=f2bf(ra0.z); w_[3]=f2bf(ra0.w);\
    w_[4]=f2bf(ra1.x); w_[5]=f2bf(ra1.y); w_[6]=f2bf(ra1.z); w_[7]=f2bf(ra1.w);\
    *reinterpret_cast<ushort8_t*>(&Al[ab][aW0]) = w_;                        \
    w_[0]=f2bf(ra2.x); w_[1]=f2bf(ra2.y); w_[2]=f2bf(ra2.z); w_[3]=f2bf(ra2.w);\
    w_[4]=f2bf(ra3.x); w_[5]=f2bf(ra3.y); w_[6]=f2bf(ra3.z); w_[7]=f2bf(ra3.w);\
    *reinterpret_cast<ushort8_t*>(&Al[ab][aW1]) = w_; } while (0)

  const f32x4 fzero = {0.f, 0.f, 0.f, 0.f};
  f32x4 acc[2][4];
#pragma unroll
  for (int i = 0; i < 2; ++i)
#pragma unroll
    for (int j = 0; j < 4; ++j) acc[i][j] = fzero;

  const int KT = Dd / BK;  // 16

  // ---- prologue: A(0)->regs; B(0),B(1) in flight; A(0)->LDS; A(1)->regs ----
  LOADA(0);
#pragma unroll
  for (int i = 0; i < 4; ++i) gload_lds16(bSrc[i], &Bl[0][bOff[i]]);
#pragma unroll
  for (int i = 0; i < 4; ++i) gload_lds16(bSrc[i] + BK, &Bl[1][bOff[i]]);
  asm volatile("s_waitcnt vmcnt(8)" ::: "memory");   // A(0) landed (compiler re-checks)
  __builtin_amdgcn_sched_barrier(0);
  WRITEA(0);
  LOADA(1);
  asm volatile("s_waitcnt vmcnt(8)" ::: "memory");   // B(0) landed
  asm volatile("s_waitcnt lgkmcnt(0)" ::: "memory"); // A(0) ds_writes done
  __builtin_amdgcn_sched_barrier(0);
  __builtin_amdgcn_s_barrier();

  for (int j = 0; j < KT; ++j) {
    int acur = j & 1;
    int bcur = j % 3;
    __builtin_amdgcn_sched_barrier(0);
    // issue B(j+2) -> bufB[(j+2)%3] (its readers finished at iter j-1's barrier)
    if (j + 2 < KT) {
      int nb = (j + 2) % 3, ko = (j + 2) * BK;
#pragma unroll
      for (int i = 0; i < 4; ++i) gload_lds16(bSrc[i] + ko, &Bl[nb][bOff[i]]);
    }
    // land A(j+1) (and B(j+1)); write A(j+1) -> bufA[acur^1]; issue A(j+2)
    if (j + 1 < KT) {
      if (j + 2 < KT) {
        asm volatile("s_waitcnt vmcnt(4)" ::: "memory");
      } else {
        asm volatile("s_waitcnt vmcnt(0)" ::: "memory");
      }
      __builtin_amdgcn_sched_barrier(0);
      WRITEA(acur ^ 1);
      if (j + 2 < KT) LOADA(j + 2);
    }
    // compute tile j
#pragma unroll
    for (int kk = 0; kk < 2; ++kk) {
      bf16x8 af[2], bf[4];
#pragma unroll
      for (int mi = 0; mi < 2; ++mi) {
        int row  = wm * 32 + mi * 16 + (lane & 15);
        int slot = (kk * 4 + (lane >> 4)) ^ (row & 7);
        af[mi] = *reinterpret_cast<const bf16x8*>(&Al[acur][row * BK + slot * 8]);
      }
#pragma unroll
      for (int ni = 0; ni < 4; ++ni) {
        int row  = wn * 64 + ni * 16 + (lane & 15);
        int slot = (kk * 4 + (lane >> 4)) ^ (row & 7);
        bf[ni] = *reinterpret_cast<const bf16x8*>(&Bl[bcur][row * BK + slot * 8]);
      }
      __builtin_amdgcn_s_setprio(1);
#pragma unroll
      for (int mi = 0; mi < 2; ++mi)
#pragma unroll
        for (int ni = 0; ni < 4; ++ni)
          acc[mi][ni] = __builtin_amdgcn_mfma_f32_16x16x32_bf16(af[mi], bf[ni], acc[mi][ni], 0, 0, 0);
      __builtin_amdgcn_s_setprio(0);
    }
    asm volatile("s_waitcnt lgkmcnt(0)" ::: "memory");  // my ds_writes + frag reads done
    __builtin_amdgcn_sched_barrier(0);
    if (j + 1 < KT) __builtin_amdgcn_s_barrier();
  }

  // epilogue: D layout col=lane&15, row=(lane>>4)*4+r  [m89-verified]
#pragma unroll
  for (int mi = 0; mi < 2; ++mi) {
    int rb = m0 + wm * 32 + mi * 16 + (lane >> 4) * 4;
#pragma unroll
    for (int r = 0; r < 4; ++r) {
      int mrow = rb + r;
      if (mrow < Mc) {
        int tok = buck[mrow];
        float* orow = out + (size_t)tok * Oo;
#pragma unroll
        for (int ni = 0; ni < 4; ++ni) {
          int col = n0 + wn * 64 + ni * 16 + (lane & 15);
          orow[col] = acc[mi][ni][r] + bias[c * Oo + col];
        }
      }
    }
  }
#undef LOADA
#undef WRITEA
}

extern "C" void kernel_launch(void* const* d_in, const int* in_sizes, int n_in,
                              void* d_out, int out_size, void* d_ws, size_t ws_size,
                              hipStream_t stream) {
  const float* x    = (const float*)d_in[0];
  const int*   cid  = (const int*)d_in[1];
  const float* W    = (const float*)d_in[2];
  const float* bias = (const float*)d_in[3];
  float* out = (float*)d_out;

  int T = in_sizes[1];            // 4096
  int D = in_sizes[0] / T;        // 1024
  int O = out_size / T;           // 1024
  int C = in_sizes[3] / O;        // 8

  char* ws = (char*)d_ws;
  int* counts = (int*)ws;                                   // C ints
  int* bucket = (int*)(ws + 64);                            // C*T ints
  unsigned short* Wt = (unsigned short*)(ws + 64 + (size_t)C * T * 4);  // C*O*D bf16

  hipMemsetAsync(counts, 0, C * sizeof(int), stream);
  k_prep<<<dim3(O / 64, D / 64, C), 256, 0, stream>>>(W, Wt, D, O, cid, counts, bucket, T);
  k_ggemm<<<dim3(C, O / BN, (T + BM - 1) / BM), 256, 0, stream>>>(
      x, Wt, bias, counts, bucket, out, T, D, O);
}

// Round 6
// 72.651 us; speedup vs baseline: 1.0737x; 1.0737x over previous
//
#include <hip/hip_runtime.h>

// CategorySpecificLinear: out[t] = x[t] @ W[cid[t]] + bias[cid[t]]
// Pipeline (3 dispatches): memset counts -> k_prep {W transpose->bf16 + bucketize}
//   -> k_ggemm (A: fp32 direct via global_load_lds + in-reg cvt; B: bf16 Wt via
//      global_load_lds; depth-2 drain sync [R2-proven]; cat->XCD L2 partition [R4-proven]).

typedef __attribute__((ext_vector_type(8))) short bf16x8;
typedef __attribute__((ext_vector_type(4))) float f32x4;
typedef __attribute__((ext_vector_type(8))) unsigned short ushort8_t;

__device__ __forceinline__ unsigned short f2bf(float f) {
  unsigned u = __float_as_uint(f);
  u += 0x7FFFu + ((u >> 16) & 1u);   // round-to-nearest-even
  return (unsigned short)(u >> 16);
}

// async global->LDS, 16B per lane; LDS dest = wave-uniform base + lane*16
__device__ __forceinline__ void gload_lds16(const void* g, void* l) {
  __builtin_amdgcn_global_load_lds(
      (const __attribute__((address_space(1))) unsigned int*)g,
      (__attribute__((address_space(3))) unsigned int*)l, 16, 0, 0);
}

// ---- kernel 1: prep = W[c][d][o] fp32 -> Wt[c][o][d] bf16  (+ bucketize on first blocks)
__global__ void k_prep(const float* __restrict__ W, unsigned short* __restrict__ Wt,
                       int Dd, int Oo,
                       const int* __restrict__ cid, int* __restrict__ counts,
                       int* __restrict__ bucket, int T) {
  int b   = blockIdx.x;
  int tid = threadIdx.x;
  // bucketize rides the first ceil(T/256) blocks
  int tok = b * 256 + tid;
  if (tok < T && b < (T + 255) / 256) {
    int cc = cid[tok];
    int p = atomicAdd(&counts[cc], 1);
    bucket[cc * T + p] = tok;
  }

  // transpose tile decode: tiles per category = (D/64)*(O/64)
  int tpc = (Dd / 64) * (Oo / 64);
  int c   = b / tpc;
  int rem = b % tpc;
  int d0  = (rem / (Oo / 64)) * 64;
  int o0  = (rem % (Oo / 64)) * 64;

  __shared__ float t[64][65];
  const float* Wc = W + (size_t)c * Dd * Oo;
#pragma unroll
  for (int p = 0; p < 4; ++p) {
    int chunk = p * 256 + tid;
    int r  = chunk >> 4;
    int cb = chunk & 15;
    float4 v = *reinterpret_cast<const float4*>(Wc + (size_t)(d0 + r) * Oo + o0 + cb * 4);
    t[r][cb * 4 + 0] = v.x; t[r][cb * 4 + 1] = v.y;
    t[r][cb * 4 + 2] = v.z; t[r][cb * 4 + 3] = v.w;
  }
  __syncthreads();
  unsigned short* Wtc = Wt + (size_t)c * Oo * Dd;
#pragma unroll
  for (int p = 0; p < 2; ++p) {
    int chunk = p * 256 + tid;
    int orow = chunk >> 3;
    int dseg = chunk & 7;
    ushort8_t w;
#pragma unroll
    for (int j = 0; j < 8; ++j) w[j] = f2bf(t[dseg * 8 + j][orow]);
    *reinterpret_cast<ushort8_t*>(Wtc + (size_t)(o0 + orow) * Dd + d0 + dseg * 8) = w;
  }
}

// ---- kernel 2: grouped GEMM ----
// Grid (C, N, M): wgid % 8 == c -> XCD c; per-XCD set = Wt_c (2MB) + x_c (2MB) -> L2.
#define BM 64
#define BN 128
#define BK 64
#define TA (BM * BK)   // fp32 elems, 16KB/stage
#define TB (BN * BK)   // bf16 elems, 16KB/stage

__global__ __launch_bounds__(256) void k_ggemm(
    const float* __restrict__ x, const unsigned short* __restrict__ Wt,
    const float* __restrict__ bias, const int* __restrict__ counts,
    const int* __restrict__ bucket, float* __restrict__ out,
    int T, int Dd, int Oo) {
  int c  = blockIdx.x;
  int Mc = counts[c];
  int m0 = blockIdx.z * BM;
  if (m0 >= Mc) return;  // block-uniform exit
  int n0 = blockIdx.y * BN;

  __shared__ __align__(16) float          Afp[2][TA];  // 32KB, A fp32 depth-2
  __shared__ __align__(16) unsigned short Bl[2][TB];   // 32KB, B bf16 depth-2

  const int tid  = threadIdx.x;
  const int lane = tid & 63;
  const int wid  = tid >> 6;
  const int wm   = wid >> 1, wn = wid & 1;  // 2x2 waves, each 32x64 of C

  const int* buck = bucket + c * T;
  const unsigned short* Wc = Wt + (size_t)c * Oo * Dd;

  // A staging: 4 gloads/wave/tile; load i covers rows [wid*16+i*4, +4) (256B fp32 rows).
  // Linear LDS dest; 16B chunk index pre-swizzled: chunk = (lane&15) ^ (row&15). [rule 21]
  const float* aSrc[4];
  int aOff[4];  // wave-uniform, float elems
#pragma unroll
  for (int i = 0; i < 4; ++i) {
    int row   = wid * 16 + i * 4 + (lane >> 4);
    int chunk = (lane & 15) ^ (row & 15);
    int mr    = m0 + row;
    int tok   = buck[mr < Mc ? mr : Mc - 1];  // clamp; masked at epilogue
    aSrc[i]   = x + (size_t)tok * Dd + chunk * 4;
    aOff[i]   = (wid * 16 + i * 4) * BK;
  }
  // B staging: 4 gloads/wave/tile; rows [wid*32+i*8, +8) (128B bf16 rows).
  // chunk = (lane&7) ^ (row&7). [proven R1-R4]
  const unsigned short* bSrc[4];
  int bOff[4];
#pragma unroll
  for (int i = 0; i < 4; ++i) {
    int row = wid * 32 + i * 8 + (lane >> 3);
    int seg = (lane & 7) ^ (row & 7);
    bSrc[i] = Wc + (size_t)(n0 + row) * Dd + seg * 8;
    bOff[i] = (wid * 32 + i * 8) * BK;
  }

  const f32x4 fzero = {0.f, 0.f, 0.f, 0.f};
  f32x4 acc[2][4];
#pragma unroll
  for (int i = 0; i < 2; ++i)
#pragma unroll
    for (int j = 0; j < 4; ++j) acc[i][j] = fzero;

  const int KT = Dd / BK;  // 16

  // prologue: stage tile 0
#pragma unroll
  for (int i = 0; i < 4; ++i) {
    gload_lds16(aSrc[i], &Afp[0][aOff[i]]);
    gload_lds16(bSrc[i], &Bl[0][bOff[i]]);
  }
  asm volatile("s_waitcnt vmcnt(0)" ::: "memory");
  __builtin_amdgcn_sched_barrier(0);
  __builtin_amdgcn_s_barrier();

  for (int kt = 0; kt < KT; ++kt) {
    int cur = kt & 1;
    // issue tile kt+1 into the other buffer (its readers finished before last barrier)
    if (kt + 1 < KT) {
      int ko = (kt + 1) * BK;
      int nb = cur ^ 1;
#pragma unroll
      for (int i = 0; i < 4; ++i) {
        gload_lds16(aSrc[i] + ko, &Afp[nb][aOff[i]]);
        gload_lds16(bSrc[i] + ko, &Bl[nb][bOff[i]]);
      }
    }
    // compute tile kt
#pragma unroll
    for (int kk = 0; kk < 2; ++kk) {
      bf16x8 af[2], bf[4];
#pragma unroll
      for (int mi = 0; mi < 2; ++mi) {
        int row = wm * 32 + mi * 16 + (lane & 15);
        int s0  = kk * 8 + (lane >> 4) * 2;          // logical 16B chunk (k-low)
        int p0  = (s0    ) ^ (row & 15);
        int p1  = (s0 + 1) ^ (row & 15);
        f32x4 lo = *reinterpret_cast<const f32x4*>(&Afp[cur][row * BK + p0 * 4]);
        f32x4 hi = *reinterpret_cast<const f32x4*>(&Afp[cur][row * BK + p1 * 4]);
        ushort8_t w;
        w[0] = f2bf(lo[0]); w[1] = f2bf(lo[1]); w[2] = f2bf(lo[2]); w[3] = f2bf(lo[3]);
        w[4] = f2bf(hi[0]); w[5] = f2bf(hi[1]); w[6] = f2bf(hi[2]); w[7] = f2bf(hi[3]);
        af[mi] = *reinterpret_cast<bf16x8*>(&w);
      }
#pragma unroll
      for (int ni = 0; ni < 4; ++ni) {
        int row  = wn * 64 + ni * 16 + (lane & 15);
        int slot = (kk * 4 + (lane >> 4)) ^ (row & 7);
        bf[ni] = *reinterpret_cast<const bf16x8*>(&Bl[cur][row * BK + slot * 8]);
      }
      __builtin_amdgcn_s_setprio(1);
#pragma unroll
      for (int mi = 0; mi < 2; ++mi)
#pragma unroll
        for (int ni = 0; ni < 4; ++ni)
          acc[mi][ni] = __builtin_amdgcn_mfma_f32_16x16x32_bf16(af[mi], bf[ni], acc[mi][ni], 0, 0, 0);
      __builtin_amdgcn_s_setprio(0);
    }
    if (kt + 1 < KT) {
      asm volatile("s_waitcnt vmcnt(0)" ::: "memory");  // tile kt+1 landed (all my loads)
      __builtin_amdgcn_sched_barrier(0);
      __builtin_amdgcn_s_barrier();
    }
  }

  // epilogue: D layout col=lane&15, row=(lane>>4)*4+r  [m89-verified]
#pragma unroll
  for (int mi = 0; mi < 2; ++mi) {
    int rb = m0 + wm * 32 + mi * 16 + (lane >> 4) * 4;
#pragma unroll
    for (int r = 0; r < 4; ++r) {
      int mrow = rb + r;
      if (mrow < Mc) {
        int tok = buck[mrow];
        float* orow = out + (size_t)tok * Oo;
#pragma unroll
        for (int ni = 0; ni < 4; ++ni) {
          int col = n0 + wn * 64 + ni * 16 + (lane & 15);
          orow[col] = acc[mi][ni][r] + bias[c * Oo + col];
        }
      }
    }
  }
}

extern "C" void kernel_launch(void* const* d_in, const int* in_sizes, int n_in,
                              void* d_out, int out_size, void* d_ws, size_t ws_size,
                              hipStream_t stream) {
  const float* x    = (const float*)d_in[0];
  const int*   cid  = (const int*)d_in[1];
  const float* W    = (const float*)d_in[2];
  const float* bias = (const float*)d_in[3];
  float* out = (float*)d_out;

  int T = in_sizes[1];            // 4096
  int D = in_sizes[0] / T;        // 1024
  int O = out_size / T;           // 1024
  int C = in_sizes[3] / O;        // 8

  char* ws = (char*)d_ws;
  int* counts = (int*)ws;                                   // C ints
  int* bucket = (int*)(ws + 64);                            // C*T ints
  unsigned short* Wt = (unsigned short*)(ws + 64 + (size_t)C * T * 4);  // C*O*D bf16

  hipMemsetAsync(counts, 0, C * sizeof(int), stream);
  int prep_blocks = C * (D / 64) * (O / 64);  // 2048 >= ceil(T/256)
  k_prep<<<prep_blocks, 256, 0, stream>>>(W, Wt, D, O, cid, counts, bucket, T);
  k_ggemm<<<dim3(C, O / BN, (T + BM - 1) / BM), 256, 0, stream>>>(
      x, Wt, bias, counts, bucket, out, T, D, O);
}

// Round 7
// 61.502 us; speedup vs baseline: 1.2683x; 1.1813x over previous
//
#include <hip/hip_runtime.h>

// CategorySpecificLinear: out[t] = x[t] @ W[cid[t]] + bias[cid[t]]
// Pipeline (3 dispatches): memset counts
//   -> k_prep {W transpose->bf16 || x cvt->bf16 || bucketize}  (role by blockIdx)
//   -> k_ggemm == Round-4 kernel verbatim (bf16 A from xb via global_load_lds,
//      depth-3 counted vmcnt(6), BM=64/BN=128/BK=64, cat->XCD L2 partition).

typedef __attribute__((ext_vector_type(8))) short bf16x8;
typedef __attribute__((ext_vector_type(4))) float f32x4;
typedef __attribute__((ext_vector_type(8))) unsigned short ushort8_t;

__device__ __forceinline__ unsigned short f2bf(float f) {
  unsigned u = __float_as_uint(f);
  u += 0x7FFFu + ((u >> 16) & 1u);   // round-to-nearest-even
  return (unsigned short)(u >> 16);
}

// async global->LDS, 16B per lane; LDS dest = wave-uniform base + lane*16
__device__ __forceinline__ void gload_lds16(const unsigned short* g, unsigned short* l) {
  __builtin_amdgcn_global_load_lds(
      (const __attribute__((address_space(1))) unsigned int*)g,
      (__attribute__((address_space(3))) unsigned int*)l, 16, 0, 0);
}

// ---- kernel 1: fused prep ----
// blocks [0, tpw):            W[c][d][o] fp32 -> Wt[c][o][d] bf16 (64x64 LDS tiles)
//   (first ceil(T/256) of these also bucketize)
// blocks [tpw, tpw + cvtb):   x fp32 -> xb bf16, 8 elems/thread
__global__ void k_prep(const float* __restrict__ W, unsigned short* __restrict__ Wt,
                       int Dd, int Oo,
                       const float* __restrict__ x, unsigned short* __restrict__ xb, int nX,
                       const int* __restrict__ cid, int* __restrict__ counts,
                       int* __restrict__ bucket, int T, int tpw) {
  int b   = blockIdx.x;
  int tid = threadIdx.x;

  if (b >= tpw) {  // ---- cvt role ----
    int i = ((b - tpw) * 256 + tid) * 8;
    if (i >= nX) return;
    float4 a0 = *reinterpret_cast<const float4*>(x + i);
    float4 a1 = *reinterpret_cast<const float4*>(x + i + 4);
    ushort8_t o;
    o[0] = f2bf(a0.x); o[1] = f2bf(a0.y); o[2] = f2bf(a0.z); o[3] = f2bf(a0.w);
    o[4] = f2bf(a1.x); o[5] = f2bf(a1.y); o[6] = f2bf(a1.z); o[7] = f2bf(a1.w);
    *reinterpret_cast<ushort8_t*>(xb + i) = o;
    return;
  }

  // ---- transpose role (+ bucketize on first blocks) ----
  int tok = b * 256 + tid;
  if (tok < T && b < (T + 255) / 256) {
    int cc = cid[tok];
    int p = atomicAdd(&counts[cc], 1);
    bucket[cc * T + p] = tok;
  }

  int tpc = (Dd / 64) * (Oo / 64);
  int c   = b / tpc;
  int rem = b % tpc;
  int d0  = (rem / (Oo / 64)) * 64;
  int o0  = (rem % (Oo / 64)) * 64;

  __shared__ float t[64][65];
  const float* Wc = W + (size_t)c * Dd * Oo;
#pragma unroll
  for (int p = 0; p < 4; ++p) {
    int chunk = p * 256 + tid;
    int r  = chunk >> 4;
    int cb = chunk & 15;
    float4 v = *reinterpret_cast<const float4*>(Wc + (size_t)(d0 + r) * Oo + o0 + cb * 4);
    t[r][cb * 4 + 0] = v.x; t[r][cb * 4 + 1] = v.y;
    t[r][cb * 4 + 2] = v.z; t[r][cb * 4 + 3] = v.w;
  }
  __syncthreads();
  unsigned short* Wtc = Wt + (size_t)c * Oo * Dd;
#pragma unroll
  for (int p = 0; p < 2; ++p) {
    int chunk = p * 256 + tid;
    int orow = chunk >> 3;
    int dseg = chunk & 7;
    ushort8_t w;
#pragma unroll
    for (int j = 0; j < 8; ++j) w[j] = f2bf(t[dseg * 8 + j][orow]);
    *reinterpret_cast<ushort8_t*>(Wtc + (size_t)(o0 + orow) * Dd + d0 + dseg * 8) = w;
  }
}

// ---- kernel 2: grouped GEMM (Round-4 verbatim) ----
// Grid (C, N, M): wgid % 8 == c -> XCD c; per-XCD set = Wt_c (2MB) + xb_c (1MB) -> L2.
#define BM 64
#define BN 128
#define BK 64
#define TILE_A (BM * BK)   // 4096 elems = 8KB
#define TILE_B (BN * BK)   // 8192 elems = 16KB

__global__ __launch_bounds__(256) void k_ggemm(
    const unsigned short* __restrict__ xb, const unsigned short* __restrict__ Wt,
    const float* __restrict__ bias, const int* __restrict__ counts,
    const int* __restrict__ bucket, float* __restrict__ out,
    int T, int Dd, int Oo) {
  int c  = blockIdx.x;
  int Mc = counts[c];
  int m0 = blockIdx.z * BM;
  if (m0 >= Mc) return;  // block-uniform exit
  int n0 = blockIdx.y * BN;

  extern __shared__ __align__(16) unsigned short smem[];  // 72KB dynamic
  unsigned short* Al = smem;                 // 3 x TILE_A
  unsigned short* Bl = smem + 3 * TILE_A;    // 3 x TILE_B

  const int tid  = threadIdx.x;
  const int lane = tid & 63;
  const int wid  = tid >> 6;
  const int wm   = wid >> 1, wn = wid & 1;  // 2x2 waves, each 32x64 of C

  const int* buck = bucket + c * T;
  const unsigned short* Wc = Wt + (size_t)c * Oo * Dd;

  // staging: per wave 2 A-gloads + 4 B-gloads per tile. Linear LDS dest;
  // global source seg pre-swizzled (seg = (lane&7) ^ (row&7)). [rule 21, R1-R4 proven]
  const unsigned short* aSrc[2];
  const unsigned short* bSrc[4];
  int aOff[2], bOff[4];  // wave-uniform LDS element offsets
#pragma unroll
  for (int i = 0; i < 2; ++i) {
    int row = wid * 16 + i * 8 + (lane >> 3);
    int seg = (lane & 7) ^ (row & 7);
    int mr  = m0 + row;
    int tok = buck[mr < Mc ? mr : Mc - 1];  // clamp; masked at epilogue
    aSrc[i] = xb + (size_t)tok * Dd + seg * 8;
    aOff[i] = (wid * 16 + i * 8) * BK;
  }
#pragma unroll
  for (int i = 0; i < 4; ++i) {
    int row = wid * 32 + i * 8 + (lane >> 3);
    int seg = (lane & 7) ^ (row & 7);
    bSrc[i] = Wc + (size_t)(n0 + row) * Dd + seg * 8;
    bOff[i] = (wid * 32 + i * 8) * BK;
  }

  const f32x4 fzero = {0.f, 0.f, 0.f, 0.f};
  f32x4 acc[2][4];
#pragma unroll
  for (int i = 0; i < 2; ++i)
#pragma unroll
    for (int j = 0; j < 4; ++j) acc[i][j] = fzero;

  const int KT = Dd / BK;  // 16

  // prologue: issue tiles 0 and 1 (6 gloads each per wave)
#pragma unroll
  for (int t8 = 0; t8 < 2; ++t8) {
    unsigned short* Ab = Al + t8 * TILE_A;
    unsigned short* Bb = Bl + t8 * TILE_B;
    int ko = t8 * BK;
#pragma unroll
    for (int i = 0; i < 2; ++i) gload_lds16(aSrc[i] + ko, Ab + aOff[i]);
#pragma unroll
    for (int i = 0; i < 4; ++i) gload_lds16(bSrc[i] + ko, Bb + bOff[i]);
  }

  int cur = 0;
  for (int kt = 0; kt < KT; ++kt) {
    // my prev ds_reads drained; tile kt's 6 loads landed (6 newer may stay in flight)
    asm volatile("s_waitcnt lgkmcnt(0)" ::: "memory");
    if (kt < KT - 1) {
      asm volatile("s_waitcnt vmcnt(6)" ::: "memory");
    } else {
      asm volatile("s_waitcnt vmcnt(0)" ::: "memory");
    }
    __builtin_amdgcn_sched_barrier(0);
    __builtin_amdgcn_s_barrier();
    __builtin_amdgcn_sched_barrier(0);

    if (kt + 2 < KT) {
      int nb = cur + 2; if (nb >= 3) nb -= 3;
      int ko = (kt + 2) * BK;
      unsigned short* An = Al + nb * TILE_A;
      unsigned short* Bn = Bl + nb * TILE_B;
#pragma unroll
      for (int i = 0; i < 2; ++i) gload_lds16(aSrc[i] + ko, An + aOff[i]);
#pragma unroll
      for (int i = 0; i < 4; ++i) gload_lds16(bSrc[i] + ko, Bn + bOff[i]);
    }

    const unsigned short* Ac = Al + cur * TILE_A;
    const unsigned short* Bc = Bl + cur * TILE_B;
#pragma unroll
    for (int kk = 0; kk < 2; ++kk) {
      bf16x8 af[2], bf[4];
#pragma unroll
      for (int mi = 0; mi < 2; ++mi) {
        int row  = wm * 32 + mi * 16 + (lane & 15);
        int slot = (kk * 4 + (lane >> 4)) ^ (row & 7);
        af[mi] = *reinterpret_cast<const bf16x8*>(&Ac[row * BK + slot * 8]);
      }
#pragma unroll
      for (int ni = 0; ni < 4; ++ni) {
        int row  = wn * 64 + ni * 16 + (lane & 15);
        int slot = (kk * 4 + (lane >> 4)) ^ (row & 7);
        bf[ni] = *reinterpret_cast<const bf16x8*>(&Bc[row * BK + slot * 8]);
      }
      __builtin_amdgcn_s_setprio(1);
#pragma unroll
      for (int mi = 0; mi < 2; ++mi)
#pragma unroll
        for (int ni = 0; ni < 4; ++ni)
          acc[mi][ni] = __builtin_amdgcn_mfma_f32_16x16x32_bf16(af[mi], bf[ni], acc[mi][ni], 0, 0, 0);
      __builtin_amdgcn_s_setprio(0);
    }
    cur = (cur + 1 == 3) ? 0 : cur + 1;
  }

  // epilogue: D layout col=lane&15, row=(lane>>4)*4+r  [m89-verified]
#pragma unroll
  for (int mi = 0; mi < 2; ++mi) {
    int rb = m0 + wm * 32 + mi * 16 + (lane >> 4) * 4;
#pragma unroll
    for (int r = 0; r < 4; ++r) {
      int mrow = rb + r;
      if (mrow < Mc) {
        int tok = buck[mrow];
        float* orow = out + (size_t)tok * Oo;
#pragma unroll
        for (int ni = 0; ni < 4; ++ni) {
          int col = n0 + wn * 64 + ni * 16 + (lane & 15);
          orow[col] = acc[mi][ni][r] + bias[c * Oo + col];
        }
      }
    }
  }
}

extern "C" void kernel_launch(void* const* d_in, const int* in_sizes, int n_in,
                              void* d_out, int out_size, void* d_ws, size_t ws_size,
                              hipStream_t stream) {
  const float* x    = (const float*)d_in[0];
  const int*   cid  = (const int*)d_in[1];
  const float* W    = (const float*)d_in[2];
  const float* bias = (const float*)d_in[3];
  float* out = (float*)d_out;

  int T = in_sizes[1];            // 4096
  int D = in_sizes[0] / T;        // 1024
  int O = out_size / T;           // 1024
  int C = in_sizes[3] / O;        // 8

  char* ws = (char*)d_ws;
  int* counts = (int*)ws;                                   // C ints
  int* bucket = (int*)(ws + 64);                            // C*T ints
  unsigned short* xb = (unsigned short*)(ws + 64 + (size_t)C * T * 4);  // T*D bf16
  unsigned short* Wt = xb + (size_t)T * D;                  // C*O*D bf16

  hipMemsetAsync(counts, 0, C * sizeof(int), stream);
  int tpw  = C * (D / 64) * (O / 64);            // 2048 transpose blocks
  int cvtb = (T * D / 8 + 255) / 256;            // 2048 cvt blocks
  k_prep<<<tpw + cvtb, 256, 0, stream>>>(W, Wt, D, O, x, xb, T * D, cid, counts, bucket, T, tpw);
  size_t ldsBytes = (size_t)3 * (TILE_A + TILE_B) * sizeof(unsigned short);  // 72KB
  k_ggemm<<<dim3(C, O / BN, (T + BM - 1) / BM), 256, ldsBytes, stream>>>(
      xb, Wt, bias, counts, bucket, out, T, D, O);
}

// Round 8
// 48.401 us; speedup vs baseline: 1.6116x; 1.2707x over previous
//
#include <hip/hip_runtime.h>

// CategorySpecificLinear: out[t] = x[t] @ W[cid[t]] + bias[cid[t]]
// Pipeline (2 dispatches, no memset):
//   k_prep: block 0 = deterministic bucketize (scan, no atomics);
//           blocks [1, tpw] = W[c][d][o] fp32 -> Wt[c][o][d] bf16;
//           blocks (tpw, tpw+cvtb] = x fp32 -> xb bf16.
//   k_ggemm: grouped GEMM, 8 waves/block (16 waves/CU), BM64/BN128/BK64,
//            depth-3 counted vmcnt(3), cat->XCD L2 partition.

typedef __attribute__((ext_vector_type(8))) short bf16x8;
typedef __attribute__((ext_vector_type(4))) float f32x4;
typedef __attribute__((ext_vector_type(8))) unsigned short ushort8_t;

__device__ __forceinline__ unsigned short f2bf(float f) {
  unsigned u = __float_as_uint(f);
  u += 0x7FFFu + ((u >> 16) & 1u);   // round-to-nearest-even
  return (unsigned short)(u >> 16);
}

// async global->LDS, 16B per lane; LDS dest = wave-uniform base + lane*16
__device__ __forceinline__ void gload_lds16(const unsigned short* g, unsigned short* l) {
  __builtin_amdgcn_global_load_lds(
      (const __attribute__((address_space(1))) unsigned int*)g,
      (__attribute__((address_space(3))) unsigned int*)l, 16, 0, 0);
}

#define MAXC 8

// ---- kernel 1: fused prep ----
__global__ void k_prep(const float* __restrict__ W, unsigned short* __restrict__ Wt,
                       int Dd, int Oo,
                       const float* __restrict__ x, unsigned short* __restrict__ xb, int nX,
                       const int* __restrict__ cid, int* __restrict__ counts,
                       int* __restrict__ bucket, int T, int C, int tpw) {
  int b   = blockIdx.x;
  int tid = threadIdx.x;

  if (b == 0) {
    // ---- deterministic bucketize: one block, 256 threads ----
    __shared__ int cnt[256][MAXC];   // per-thread per-category counts -> offsets
    int tpt = (T + 255) / 256;       // tokens per thread
    int t0  = tid * tpt;
    int t1  = min(t0 + tpt, T);
    for (int c = 0; c < C; ++c) cnt[tid][c] = 0;
    for (int t = t0; t < t1; ++t) cnt[tid][cid[t]]++;
    __syncthreads();
    if (tid < C) {  // exclusive scan over threads, per category
      int run = 0;
      for (int t = 0; t < 256; ++t) { int v = cnt[t][tid]; cnt[t][tid] = run; run += v; }
      counts[tid] = run;
    }
    __syncthreads();
    for (int t = t0; t < t1; ++t) {
      int c = cid[t];
      int p = cnt[tid][c]++;   // thread-private LDS row, no race
      bucket[c * T + p] = t;
    }
    return;
  }

  if (b > tpw) {  // ---- cvt role: x fp32 -> bf16, 8 elems/thread ----
    int i = ((b - tpw - 1) * 256 + tid) * 8;
    if (i >= nX) return;
    float4 a0 = *reinterpret_cast<const float4*>(x + i);
    float4 a1 = *reinterpret_cast<const float4*>(x + i + 4);
    ushort8_t o;
    o[0] = f2bf(a0.x); o[1] = f2bf(a0.y); o[2] = f2bf(a0.z); o[3] = f2bf(a0.w);
    o[4] = f2bf(a1.x); o[5] = f2bf(a1.y); o[6] = f2bf(a1.z); o[7] = f2bf(a1.w);
    *reinterpret_cast<ushort8_t*>(xb + i) = o;
    return;
  }

  // ---- transpose role: 64x64 tile of W[c] ----
  int bb  = b - 1;
  int tpc = (Dd / 64) * (Oo / 64);
  int c   = bb / tpc;
  int rem = bb % tpc;
  int d0  = (rem / (Oo / 64)) * 64;
  int o0  = (rem % (Oo / 64)) * 64;

  __shared__ float t[64][65];
  const float* Wc = W + (size_t)c * Dd * Oo;
#pragma unroll
  for (int p = 0; p < 4; ++p) {
    int chunk = p * 256 + tid;
    int r  = chunk >> 4;
    int cb = chunk & 15;
    float4 v = *reinterpret_cast<const float4*>(Wc + (size_t)(d0 + r) * Oo + o0 + cb * 4);
    t[r][cb * 4 + 0] = v.x; t[r][cb * 4 + 1] = v.y;
    t[r][cb * 4 + 2] = v.z; t[r][cb * 4 + 3] = v.w;
  }
  __syncthreads();
  unsigned short* Wtc = Wt + (size_t)c * Oo * Dd;
#pragma unroll
  for (int p = 0; p < 2; ++p) {
    int chunk = p * 256 + tid;
    int orow = chunk >> 3;
    int dseg = chunk & 7;
    ushort8_t w;
#pragma unroll
    for (int j = 0; j < 8; ++j) w[j] = f2bf(t[dseg * 8 + j][orow]);
    *reinterpret_cast<ushort8_t*>(Wtc + (size_t)(o0 + orow) * Dd + d0 + dseg * 8) = w;
  }
}

// ---- kernel 2: grouped GEMM, 8 waves/block ----
// Grid (C, N, M): wgid % 8 == c -> XCD c; per-XCD set = Wt_c (2MB) + xb_c (1MB) -> L2.
#define BM 64
#define BN 128
#define BK 64
#define TILE_A (BM * BK)   // 4096 elems = 8KB
#define TILE_B (BN * BK)   // 8192 elems = 16KB

__global__ __launch_bounds__(512) void k_ggemm(
    const unsigned short* __restrict__ xb, const unsigned short* __restrict__ Wt,
    const float* __restrict__ bias, const int* __restrict__ counts,
    const int* __restrict__ bucket, float* __restrict__ out,
    int T, int Dd, int Oo) {
  int c  = blockIdx.x;
  int Mc = counts[c];
  int m0 = blockIdx.z * BM;
  if (m0 >= Mc) return;  // block-uniform exit
  int n0 = blockIdx.y * BN;

  extern __shared__ __align__(16) unsigned short smem[];  // 72KB dynamic
  unsigned short* Al = smem;                 // 3 x TILE_A
  unsigned short* Bl = smem + 3 * TILE_A;    // 3 x TILE_B

  const int tid  = threadIdx.x;
  const int lane = tid & 63;
  const int wid  = tid >> 6;                 // 0..7
  const int wm   = wid >> 2, wn = wid & 3;   // 2x4 waves, each 32x32 of C

  const int* buck = bucket + c * T;
  const unsigned short* Wc = Wt + (size_t)c * Oo * Dd;

  // staging: per wave 1 A-gload (rows wid*8..+8) + 2 B-gloads (rows wid*16+i*8..+8).
  // Linear LDS dest; global source seg pre-swizzled (seg = (lane&7) ^ (row&7)). [rule 21]
  const unsigned short* aSrc;
  const unsigned short* bSrc[2];
  int aOff, bOff[2];  // wave-uniform LDS element offsets
  {
    int row = wid * 8 + (lane >> 3);
    int seg = (lane & 7) ^ (row & 7);
    int mr  = m0 + row;
    int tok = buck[mr < Mc ? mr : Mc - 1];  // clamp; masked at epilogue
    aSrc = xb + (size_t)tok * Dd + seg * 8;
    aOff = (wid * 8) * BK;
  }
#pragma unroll
  for (int i = 0; i < 2; ++i) {
    int row = wid * 16 + i * 8 + (lane >> 3);
    int seg = (lane & 7) ^ (row & 7);
    bSrc[i] = Wc + (size_t)(n0 + row) * Dd + seg * 8;
    bOff[i] = (wid * 16 + i * 8) * BK;
  }

  const f32x4 fzero = {0.f, 0.f, 0.f, 0.f};
  f32x4 acc[2][2];
#pragma unroll
  for (int i = 0; i < 2; ++i)
#pragma unroll
    for (int j = 0; j < 2; ++j) acc[i][j] = fzero;

  const int KT = Dd / BK;  // 16

  // prologue: issue tiles 0 and 1 (3 gloads each per wave)
#pragma unroll
  for (int t8 = 0; t8 < 2; ++t8) {
    unsigned short* Ab = Al + t8 * TILE_A;
    unsigned short* Bb = Bl + t8 * TILE_B;
    int ko = t8 * BK;
    gload_lds16(aSrc + ko, Ab + aOff);
#pragma unroll
    for (int i = 0; i < 2; ++i) gload_lds16(bSrc[i] + ko, Bb + bOff[i]);
  }

  int cur = 0;
  for (int kt = 0; kt < KT; ++kt) {
    // my prev ds_reads drained; tile kt's 3 loads landed (3 newer may stay in flight)
    asm volatile("s_waitcnt lgkmcnt(0)" ::: "memory");
    if (kt < KT - 1) {
      asm volatile("s_waitcnt vmcnt(3)" ::: "memory");
    } else {
      asm volatile("s_waitcnt vmcnt(0)" ::: "memory");
    }
    __builtin_amdgcn_sched_barrier(0);
    __builtin_amdgcn_s_barrier();
    __builtin_amdgcn_sched_barrier(0);

    if (kt + 2 < KT) {
      int nb = cur + 2; if (nb >= 3) nb -= 3;
      int ko = (kt + 2) * BK;
      unsigned short* An = Al + nb * TILE_A;
      unsigned short* Bn = Bl + nb * TILE_B;
      gload_lds16(aSrc + ko, An + aOff);
#pragma unroll
      for (int i = 0; i < 2; ++i) gload_lds16(bSrc[i] + ko, Bn + bOff[i]);
    }

    const unsigned short* Ac = Al + cur * TILE_A;
    const unsigned short* Bc = Bl + cur * TILE_B;
#pragma unroll
    for (int kk = 0; kk < 2; ++kk) {
      bf16x8 af[2], bf[2];
#pragma unroll
      for (int mi = 0; mi < 2; ++mi) {
        int row  = wm * 32 + mi * 16 + (lane & 15);
        int slot = (kk * 4 + (lane >> 4)) ^ (row & 7);
        af[mi] = *reinterpret_cast<const bf16x8*>(&Ac[row * BK + slot * 8]);
      }
#pragma unroll
      for (int ni = 0; ni < 2; ++ni) {
        int row  = wn * 32 + ni * 16 + (lane & 15);
        int slot = (kk * 4 + (lane >> 4)) ^ (row & 7);
        bf[ni] = *reinterpret_cast<const bf16x8*>(&Bc[row * BK + slot * 8]);
      }
      __builtin_amdgcn_s_setprio(1);
#pragma unroll
      for (int mi = 0; mi < 2; ++mi)
#pragma unroll
        for (int ni = 0; ni < 2; ++ni)
          acc[mi][ni] = __builtin_amdgcn_mfma_f32_16x16x32_bf16(af[mi], bf[ni], acc[mi][ni], 0, 0, 0);
      __builtin_amdgcn_s_setprio(0);
    }
    cur = (cur + 1 == 3) ? 0 : cur + 1;
  }

  // epilogue: D layout col=lane&15, row=(lane>>4)*4+r  [m89-verified]
#pragma unroll
  for (int mi = 0; mi < 2; ++mi) {
    int rb = m0 + wm * 32 + mi * 16 + (lane >> 4) * 4;
#pragma unroll
    for (int r = 0; r < 4; ++r) {
      int mrow = rb + r;
      if (mrow < Mc) {
        int tok = buck[mrow];
        float* orow = out + (size_t)tok * Oo;
#pragma unroll
        for (int ni = 0; ni < 2; ++ni) {
          int col = n0 + wn * 32 + ni * 16 + (lane & 15);
          orow[col] = acc[mi][ni][r] + bias[c * Oo + col];
        }
      }
    }
  }
}

extern "C" void kernel_launch(void* const* d_in, const int* in_sizes, int n_in,
                              void* d_out, int out_size, void* d_ws, size_t ws_size,
                              hipStream_t stream) {
  const float* x    = (const float*)d_in[0];
  const int*   cid  = (const int*)d_in[1];
  const float* W    = (const float*)d_in[2];
  const float* bias = (const float*)d_in[3];
  float* out = (float*)d_out;

  int T = in_sizes[1];            // 4096
  int D = in_sizes[0] / T;        // 1024
  int O = out_size / T;           // 1024
  int C = in_sizes[3] / O;        // 8

  char* ws = (char*)d_ws;
  int* counts = (int*)ws;                                   // C ints
  int* bucket = (int*)(ws + 64);                            // C*T ints
  unsigned short* xb = (unsigned short*)(ws + 64 + (size_t)C * T * 4);  // T*D bf16
  unsigned short* Wt = xb + (size_t)T * D;                  // C*O*D bf16

  int tpw  = C * (D / 64) * (O / 64);            // 2048 transpose blocks
  int cvtb = (T * D / 8 + 255) / 256;            // 2048 cvt blocks
  k_prep<<<1 + tpw + cvtb, 256, 0, stream>>>(W, Wt, D, O, x, xb, T * D,
                                             cid, counts, bucket, T, C, tpw);
  size_t ldsBytes = (size_t)3 * (TILE_A + TILE_B) * sizeof(unsigned short);  // 72KB
  k_ggemm<<<dim3(C, O / BN, (T + BM - 1) / BM), 512, ldsBytes, stream>>>(
      xb, Wt, bias, counts, bucket, out, T, D, O);
}